// Round 8
// baseline (220.741 us; speedup 1.0000x reference)
//
#include <hip/hip_runtime.h>
#include <math.h>

#define B_     64
#define N_     128
#define S_     2048
#define D_     128
#define K_TOP  128
#define CAPB   1024     // per-block candidate cap
#define SELCAP 8192     // per-(batch,side) cutoff-bin list cap

typedef _Float16 f16x8 __attribute__((ext_vector_type(8)));
typedef __fp16   fp16x2 __attribute__((ext_vector_type(2)));
typedef float    f32x4 __attribute__((ext_vector_type(4)));

union Frag { uint4 u; f16x8 h; };

// Monotone mapping: float total order -> unsigned total order
__device__ __forceinline__ unsigned fkey(float x) {
    unsigned u = __float_as_uint(x);
    return (u & 0x80000000u) ? ~u : (u | 0x80000000u);
}
__device__ __forceinline__ float unkey(unsigned k) {
    unsigned u = (k & 0x80000000u) ? (k & 0x7fffffffu) : ~k;
    return __uint_as_float(u);
}

// 8 fp32 -> 8 fp16 via packed v_cvt_pkrtz (1 inst / 2 elems)
__device__ __forceinline__ uint4 pk8(float4 a, float4 b) {
    union { fp16x2 h; unsigned u; } c0, c1, c2, c3;
    c0.h = __builtin_amdgcn_cvt_pkrtz(a.x, a.y);
    c1.h = __builtin_amdgcn_cvt_pkrtz(a.z, a.w);
    c2.h = __builtin_amdgcn_cvt_pkrtz(b.x, b.y);
    c3.h = __builtin_amdgcn_cvt_pkrtz(b.z, b.w);
    return uint4{c0.u, c1.u, c2.u, c3.u};
}

// K1: fp16 MFMA GEMM (128x128 tile, K=128, BK=64).  Epilogues from registers:
//  (a) per-row max -> rowmaxLocal[slot]
//  (b) 2048-bin hist (4 bank-staggered packed replicas) -> local cutoff ->
//      candidate compaction; combined bins pushed to global ghist[z].
__global__ __launch_bounds__(256) void gemm_fused(
    const float* __restrict__ q, const float* __restrict__ dpos,
    const float* __restrict__ dneg, int nb, int b0,
    unsigned* __restrict__ rowmaxLocal,   // [2nb*16*N_]
    unsigned* __restrict__ cand,          // [2nb*16*CAPB]
    unsigned* __restrict__ candCnt,       // [2nb*16]
    unsigned* __restrict__ ghist)         // [2nb*2048], pre-zeroed
{
    __shared__ uint4 sh4[2048];           // 32 KiB
    unsigned* sw = (unsigned*)sh4;
    // epilogue aliases: hist = sw[0..4096); buf = sw[0..1024) (post-hist);
    // cbins16 @ words [4096,5120); rmx @ [5120,5248); ctrl @ [5248,5256)
    unsigned short* cbins16 = (unsigned short*)(sw + 4096);
    unsigned* rmx  = sw + 5120;
    unsigned* ctrl = sw + 5248;

    const int z  = blockIdx.z;
    const int bz = (z < nb) ? z : z - nb;
    const float* docs = (z < nb) ? dpos : dneg;
    const int bx = blockIdx.x;
    const int s0 = bx * 128;
    const float* qb = q + (size_t)(b0 + bz) * N_ * D_;
    const float* db = docs + (size_t)(b0 + bz) * S_ * D_;

    const int t    = threadIdx.x;
    const int lane = t & 63;
    const int w    = t >> 6;
    const int quad = lane >> 4;
    const int m    = lane & 15;
    const int Ibase = (w >> 1) << 2;
    const int Jbase = (w & 1) << 2;

    f32x4 acc[4][4];
    #pragma unroll
    for (int i = 0; i < 4; ++i)
        #pragma unroll
        for (int j = 0; j < 4; ++j)
            acc[i][j] = f32x4{0.f, 0.f, 0.f, 0.f};

    for (int k0 = 0; k0 < D_; k0 += 64) {
        #pragma unroll
        for (int p = 0; p < 4; ++p) {
            int ci  = t + (p << 8);
            int row = ((ci >> 7) << 4) | (ci & 15);
            int kf  = k0 + (((ci >> 4) & 7) << 3);
            const float* ga = qb + (size_t)row * D_ + kf;
            sh4[ci] = pk8(*(const float4*)ga, *(const float4*)(ga + 4));
            const float* gb = db + (size_t)(s0 + row) * D_ + kf;
            sh4[1024 + ci] = pk8(*(const float4*)gb, *(const float4*)(gb + 4));
        }
        __syncthreads();
        #pragma unroll
        for (int ks = 0; ks < 2; ++ks) {
            Frag af[4], bf[4];
            #pragma unroll
            for (int i = 0; i < 4; ++i) {
                af[i].u = sh4[(Ibase + i) * 128 + ks * 64 + lane];
                bf[i].u = sh4[1024 + (Jbase + i) * 128 + ks * 64 + lane];
            }
            #pragma unroll
            for (int i = 0; i < 4; ++i)
                #pragma unroll
                for (int j = 0; j < 4; ++j)
                    acc[i][j] = __builtin_amdgcn_mfma_f32_16x16x32_f16(
                        af[i].h, bf[j].h, acc[i][j], 0, 0, 0);
        }
        __syncthreads();
    }

    // ---- epilogue ----
    for (int i = t; i < 4096; i += 256) sw[i] = 0u;
    if (t < 128) rmx[t] = 0u;
    if (t == 0) { ctrl[0] = 0u; ctrl[1] = 0u; }
    __syncthreads();

    // rowmax + hist (C/D layout: col = lane&15, row = quad*4 + reg)
    const unsigned repw = (unsigned)((t & 3) << 10);
    const unsigned repo = (unsigned)((t & 3) << 3);
    #pragma unroll
    for (int i = 0; i < 4; ++i) {
        #pragma unroll
        for (int r = 0; r < 4; ++r) {
            unsigned ka = fkey(acc[i][0][r]);
            unsigned kb = fkey(acc[i][1][r]);
            unsigned kc = fkey(acc[i][2][r]);
            unsigned kd = fkey(acc[i][3][r]);
            unsigned km = max(max(ka, kb), max(kc, kd));
            #pragma unroll
            for (int off = 1; off < 16; off <<= 1)
                km = max(km, (unsigned)__shfl_xor((int)km, off, 64));
            if (m == 0) atomicMax(&rmx[((Ibase + i) << 4) + (quad << 2) + r], km);
            unsigned bb;
            bb = ka >> 21; atomicAdd(&sw[repw + (((bb & 1023u) + repo) & 1023u)], 1u << ((bb >> 10) << 4));
            bb = kb >> 21; atomicAdd(&sw[repw + (((bb & 1023u) + repo) & 1023u)], 1u << ((bb >> 10) << 4));
            bb = kc >> 21; atomicAdd(&sw[repw + (((bb & 1023u) + repo) & 1023u)], 1u << ((bb >> 10) << 4));
            bb = kd >> 21; atomicAdd(&sw[repw + (((bb & 1023u) + repo) & 1023u)], 1u << ((bb >> 10) << 4));
        }
    }
    __syncthreads();

    // combine replicas -> cbins16 (thread t covers bins 8t..8t+7)
    {
        const int hs = (t >= 128) ? 16 : 0;
        #pragma unroll
        for (int j = 0; j < 8; ++j) {
            int bin = (t << 3) + j;
            int wlo = bin & 1023;
            unsigned c = 0;
            #pragma unroll
            for (int rr = 0; rr < 4; ++rr)
                c += (sw[(rr << 10) + ((wlo + (rr << 3)) & 1023)] >> hs) & 0xFFFFu;
            cbins16[bin] = (unsigned short)c;
        }
    }
    __syncthreads();

    // push nonzero bins to global ghist; wave 0 finds local cutoff (shuffle scan)
    {
        unsigned* gh = ghist + (size_t)z * 2048;
        #pragma unroll
        for (int j = 0; j < 8; ++j) {
            int bin = (t << 3) + j;
            unsigned c = cbins16[bin];
            if (c) atomicAdd(&gh[bin], c);
        }
    }
    if (w == 0) {
        unsigned cs[4]; unsigned tot = 0;
        #pragma unroll
        for (int j = 0; j < 4; ++j) {
            int chunk = (lane << 2) + j;
            unsigned s = 0;
            #pragma unroll
            for (int jj = 0; jj < 8; ++jj) s += cbins16[(chunk << 3) + jj];
            cs[j] = s; tot += s;
        }
        unsigned suf = tot;
        #pragma unroll
        for (int off = 1; off < 64; off <<= 1) {
            unsigned o = (unsigned)__shfl_down((int)suf, off, 64);
            suf += (lane + off < 64) ? o : 0u;
        }
        unsigned Snx = (unsigned)__shfl_down((int)suf, 1, 64);
        if (lane == 63) Snx = 0u;
        if (suf >= K_TOP && Snx < K_TOP) {
            unsigned cum = Snx;
            unsigned lbv = (unsigned)(lane << 5);
            bool done = false;
            for (int j = 3; j >= 0 && !done; --j) {
                int chunk = (lane << 2) + j;
                if (cum + cs[j] < K_TOP) { cum += cs[j]; continue; }
                for (int bb = 7; bb >= 0; --bb) {
                    int bin = (chunk << 3) + bb;
                    unsigned hh = cbins16[bin];
                    if (cum + hh >= K_TOP) { lbv = (unsigned)bin; done = true; break; }
                    cum += hh;
                }
            }
            ctrl[0] = lbv;
        }
    }
    __syncthreads();
    const unsigned lb = ctrl[0];

    // compact keys with bin >= lb into buf (hist region dead)
    unsigned* buf = sw;
    #pragma unroll
    for (int i = 0; i < 4; ++i)
        #pragma unroll
        for (int j = 0; j < 4; ++j)
            #pragma unroll
            for (int r = 0; r < 4; ++r) {
                unsigned u = fkey(acc[i][j][r]);
                if ((u >> 21) >= lb) {
                    unsigned idx = atomicAdd(&ctrl[1], 1u);
                    if (idx < CAPB) buf[idx] = u;
                }
            }
    __syncthreads();
    const int slot = z * 16 + bx;
    unsigned c = min(ctrl[1], (unsigned)CAPB);
    for (unsigned i = t; i < c; i += 256) cand[(size_t)slot * CAPB + i] = buf[i];
    if (t == 0) candCnt[slot] = c;
    if (t < 128) rowmaxLocal[(size_t)slot * N_ + t] = rmx[t];
}

// K2: per (batch,side): exact global cutoff from ghist, resolve within the
// cutoff bin via low-21-bit radix over filtered candidates, then score.
__global__ __launch_bounds__(256) void select_score(
    const unsigned* __restrict__ ghist, const unsigned* __restrict__ cand,
    const unsigned* __restrict__ candCnt, const unsigned* __restrict__ rowmaxLocal,
    float* __restrict__ sc, int nb, int b0)
{
    __shared__ unsigned lbuf[SELCAP];
    __shared__ unsigned scanS[256];
    __shared__ unsigned h[256];
    __shared__ unsigned cnts[16];
    __shared__ unsigned ctrl[8];   // 0 gbin, 1 krem, 2 lcnt, 3..5 digits
    __shared__ float s_sum[4], s_cnt[4];
    const int z   = blockIdx.x;
    const int tid = threadIdx.x;
    const int lane = tid & 63;
    const int w    = tid >> 6;
    const unsigned* gh = ghist + (size_t)z * 2048;

    if (tid < 16) cnts[tid] = candCnt[z * 16 + tid];
    if (tid == 0) { ctrl[2] = 0u; ctrl[3] = 0u; ctrl[4] = 0u; ctrl[5] = 0u; }
    {
        unsigned s = 0;
        #pragma unroll
        for (int j = 0; j < 8; ++j) s += gh[(tid << 3) + j];
        scanS[tid] = s;
    }
    __syncthreads();
    if (w == 0) {
        unsigned cs[4]; unsigned tot = 0;
        #pragma unroll
        for (int j = 0; j < 4; ++j) { cs[j] = scanS[(lane << 2) + j]; tot += cs[j]; }
        unsigned suf = tot;
        #pragma unroll
        for (int off = 1; off < 64; off <<= 1) {
            unsigned o = (unsigned)__shfl_down((int)suf, off, 64);
            suf += (lane + off < 64) ? o : 0u;
        }
        unsigned Snx = (unsigned)__shfl_down((int)suf, 1, 64);
        if (lane == 63) Snx = 0u;
        if (suf >= K_TOP && Snx < K_TOP) {
            unsigned cum = Snx;
            for (int j = 3; j >= 0; --j) {
                int chunk = (lane << 2) + j;
                if (cum + cs[j] < K_TOP) { cum += cs[j]; continue; }
                for (int bb = 7; bb >= 0; --bb) {
                    int bin = (chunk << 3) + bb;
                    unsigned hh = gh[bin];
                    if (cum + hh >= K_TOP) {
                        ctrl[0] = (unsigned)bin;
                        ctrl[1] = K_TOP - cum;
                        j = -1; break;
                    }
                    cum += hh;
                }
            }
        }
    }
    __syncthreads();
    const unsigned gbin = ctrl[0];

    // rowmax combine + filter candidates to the cutoff bin
    unsigned myrm = 0u;
    if (tid < N_) {
        #pragma unroll
        for (int s = 0; s < 16; ++s)
            myrm = max(myrm, rowmaxLocal[(size_t)(z * 16 + s) * N_ + tid]);
    }
    for (int s = 0; s < 16; ++s) {
        const unsigned* src = cand + (size_t)(z * 16 + s) * CAPB;
        unsigned cnt = cnts[s];
        for (unsigned i = tid; i < cnt; i += 256) {
            unsigned u = src[i];
            if ((u >> 21) == gbin) {
                unsigned idx = atomicAdd(&ctrl[2], 1u);
                if (idx < SELCAP) lbuf[idx] = u;
            }
        }
    }
    __syncthreads();
    const int total = (int)min(ctrl[2], (unsigned)SELCAP);

    // 3-round radix on low 21 bits: digits [20:13], [12:5], [4:0]
    for (int r = 0; r < 3; ++r) {
        h[tid] = 0u;
        __syncthreads();
        const unsigned d1 = ctrl[3], d2 = ctrl[4];
        const unsigned k = ctrl[1];
        for (int i = tid; i < total; i += 256) {
            unsigned u = lbuf[i];
            unsigned dig; bool ok;
            if (r == 0)      { ok = true;                                 dig = (u >> 13) & 255u; }
            else if (r == 1) { ok = ((u >> 13) & 255u) == d1;             dig = (u >> 5) & 255u; }
            else             { ok = ((u >> 5) & 0xFFFFu) == ((d1 << 8) | d2); dig = u & 31u; }
            if (ok) atomicAdd(&h[dig], 1u);
        }
        __syncthreads();
        if (w == 0) {
            unsigned cs[4]; unsigned tot = 0;
            #pragma unroll
            for (int j = 0; j < 4; ++j) { cs[j] = h[(lane << 2) + j]; tot += cs[j]; }
            unsigned suf = tot;
            #pragma unroll
            for (int off = 1; off < 64; off <<= 1) {
                unsigned o = (unsigned)__shfl_down((int)suf, off, 64);
                suf += (lane + off < 64) ? o : 0u;
            }
            unsigned Snx = (unsigned)__shfl_down((int)suf, 1, 64);
            if (lane == 63) Snx = 0u;
            if (suf >= k && Snx < k) {
                unsigned cum = Snx;
                for (int j = 3; j >= 0; --j) {
                    unsigned dg = (unsigned)((lane << 2) + j);
                    if (cum + cs[j] < k) { cum += cs[j]; continue; }
                    ctrl[3 + r] = dg;
                    ctrl[1] = k - cum;
                    break;
                }
            }
        }
        __syncthreads();
    }
    const unsigned T = (gbin << 21) | (ctrl[3] << 13) | (ctrl[4] << 5) | ctrl[5];

    // score from 128 row maxima
    float v = 0.f, c = 0.f;
    if (tid < N_ && myrm >= T) { v = fmaxf(unkey(myrm), 0.f); c = 1.f; }
    #pragma unroll
    for (int off = 32; off > 0; off >>= 1) {
        v += __shfl_xor(v, off, 64);
        c += __shfl_xor(c, off, 64);
    }
    if ((tid & 63) == 0) { s_sum[w] = v; s_cnt[w] = c; }
    __syncthreads();
    if (tid == 0) {
        float Sv = s_sum[0] + s_sum[1] + s_sum[2] + s_sum[3];
        float Cv = s_cnt[0] + s_cnt[1] + s_cnt[2] + s_cnt[3];
        int b = b0 + ((z < nb) ? z : z - nb);
        int side = (z < nb) ? 0 : 1;
        sc[side * B_ + b] = Sv / fmaxf(Cv, 0.001f);
    }
}

// K3: loss = mean_b softplus(neg - pos)
__global__ __launch_bounds__(64) void final_loss(
    const float* __restrict__ sc, float* __restrict__ out)
{
    int b = threadIdx.x;
    float x = sc[B_ + b] - sc[b];
    float sp = (x > 20.f) ? x : log1pf(expf(x));
    #pragma unroll
    for (int o = 32; o > 0; o >>= 1) sp += __shfl_xor(sp, o, 64);
    if (b == 0) out[0] = sp * (1.f / B_);
}

extern "C" void kernel_launch(void* const* d_in, const int* in_sizes, int n_in,
                              void* d_out, int out_size, void* d_ws, size_t ws_size,
                              hipStream_t stream) {
    const float* q    = (const float*)d_in[0];
    const float* dpos = (const float*)d_in[1];
    const float* dneg = (const float*)d_in[2];
    float* out = (float*)d_out;
    char* ws = (char*)d_ws;

    // per-batch words (x2 sides): ghist 2048 + rowmax 16*128 + cand 16*CAPB + cnt 16
    const size_t per_batch = 2ull * (2048 + 16 * N_ + 16 * CAPB + 16) * 4;
    const size_t fixed = 2 * B_ * sizeof(float) + 256;
    size_t avail = (ws_size > fixed) ? (ws_size - fixed) : 0;
    int Bc = (int)(avail / per_batch);
    if (Bc > B_) Bc = B_;
    if (Bc < 1) Bc = 1;

    char* p = ws;
    float*    sc          = (float*)p;    p += ((2 * B_ * 4 + 255) / 256) * 256;
    unsigned* ghist       = (unsigned*)p; p += (size_t)2 * Bc * 2048 * 4;
    unsigned* rowmaxLocal = (unsigned*)p; p += (size_t)2 * Bc * 16 * N_ * 4;
    unsigned* candCnt     = (unsigned*)p; p += (size_t)2 * Bc * 16 * 4;
    unsigned* cand        = (unsigned*)p; p += (size_t)2 * Bc * 16 * CAPB * 4;

    for (int b0 = 0; b0 < B_; b0 += Bc) {
        int nb = (B_ - b0 < Bc) ? (B_ - b0) : Bc;
        (void)hipMemsetAsync(ghist, 0, (size_t)2 * nb * 2048 * 4, stream);
        gemm_fused<<<dim3(S_ / 128, 1, 2 * nb), 256, 0, stream>>>(
            q, dpos, dneg, nb, b0, rowmaxLocal, cand, candCnt, ghist);
        select_score<<<2 * nb, 256, 0, stream>>>(
            ghist, cand, candCnt, rowmaxLocal, sc, nb, b0);
    }
    final_loss<<<1, 64, 0, stream>>>(sc, out);
}

// Round 9
// 214.606 us; speedup vs baseline: 1.0286x; 1.0286x over previous
//
#include <hip/hip_runtime.h>
#include <math.h>

#define B_     64
#define N_     128
#define S_     2048
#define D_     128
#define K_TOP  128
#define CAPB   1024     // per-block candidate cap
#define SELCAP 8192     // per-(batch,side) cutoff-bin list cap

typedef _Float16 f16x8 __attribute__((ext_vector_type(8)));
typedef float    f32x4 __attribute__((ext_vector_type(4)));

union Frag { uint4 u; f16x8 h; };

// Monotone mapping: float total order -> unsigned total order
__device__ __forceinline__ unsigned fkey(float x) {
    unsigned u = __float_as_uint(x);
    return (u & 0x80000000u) ? ~u : (u | 0x80000000u);
}
__device__ __forceinline__ float unkey(unsigned k) {
    unsigned u = (k & 0x80000000u) ? (k & 0x7fffffffu) : ~k;
    return __uint_as_float(u);
}

// 8 fp32 -> 8 fp16 (RNE) packed into uint4   [R6-proven: VGPR-light]
__device__ __forceinline__ uint4 cvt8h(float4 a, float4 b) {
    union { _Float16 h[8]; uint4 u; } r;
    r.h[0] = (_Float16)a.x; r.h[1] = (_Float16)a.y;
    r.h[2] = (_Float16)a.z; r.h[3] = (_Float16)a.w;
    r.h[4] = (_Float16)b.x; r.h[5] = (_Float16)b.y;
    r.h[6] = (_Float16)b.z; r.h[7] = (_Float16)b.w;
    return r.u;
}

// K1: fp16 MFMA GEMM (128x128 tile, K=128, BK=64).  R6 epilogue + ghist push.
__global__ __launch_bounds__(256) void gemm_fused(
    const float* __restrict__ q, const float* __restrict__ dpos,
    const float* __restrict__ dneg, int nb, int b0,
    unsigned* __restrict__ rowmaxLocal,   // [2nb*16*N_]
    unsigned* __restrict__ cand,          // [2nb*16*CAPB]
    unsigned* __restrict__ candCnt,       // [2nb*16]
    unsigned* __restrict__ ghist)         // [2nb*2048], pre-zeroed
{
    __shared__ uint4 sh4[2048];           // 32 KiB
    unsigned* sw = (unsigned*)sh4;
    // epilogue aliases: hist = sw[0..4096) (2048 bins x 2 replicas);
    // scanS @ [4096,4352); buf = sw[0..1024) (post-hist); rmx @ [5376,5504);
    // ctrl @ [5504,5506)
    unsigned* scanS = sw + 4096;
    unsigned* rmx   = sw + 5376;
    unsigned* ctrl  = sw + 5504;

    const int z  = blockIdx.z;
    const int bz = (z < nb) ? z : z - nb;
    const float* docs = (z < nb) ? dpos : dneg;
    const int bx = blockIdx.x;
    const int s0 = bx * 128;
    const float* qb = q + (size_t)(b0 + bz) * N_ * D_;
    const float* db = docs + (size_t)(b0 + bz) * S_ * D_;

    const int t    = threadIdx.x;
    const int lane = t & 63;
    const int w    = t >> 6;
    const int quad = lane >> 4;
    const int m    = lane & 15;
    const int Ibase = (w >> 1) << 2;
    const int Jbase = (w & 1) << 2;

    f32x4 acc[4][4];
    #pragma unroll
    for (int i = 0; i < 4; ++i)
        #pragma unroll
        for (int j = 0; j < 4; ++j)
            acc[i][j] = f32x4{0.f, 0.f, 0.f, 0.f};

    for (int k0 = 0; k0 < D_; k0 += 64) {
        #pragma unroll
        for (int p = 0; p < 4; ++p) {
            int ci  = t + (p << 8);
            int row = ((ci >> 7) << 4) | (ci & 15);
            int kf  = k0 + (((ci >> 4) & 7) << 3);
            const float* ga = qb + (size_t)row * D_ + kf;
            sh4[ci] = cvt8h(*(const float4*)ga, *(const float4*)(ga + 4));
            const float* gb = db + (size_t)(s0 + row) * D_ + kf;
            sh4[1024 + ci] = cvt8h(*(const float4*)gb, *(const float4*)(gb + 4));
        }
        __syncthreads();
        #pragma unroll
        for (int ks = 0; ks < 2; ++ks) {
            Frag af[4], bf[4];
            #pragma unroll
            for (int i = 0; i < 4; ++i) {
                af[i].u = sh4[(Ibase + i) * 128 + ks * 64 + lane];
                bf[i].u = sh4[1024 + (Jbase + i) * 128 + ks * 64 + lane];
            }
            #pragma unroll
            for (int i = 0; i < 4; ++i)
                #pragma unroll
                for (int j = 0; j < 4; ++j)
                    acc[i][j] = __builtin_amdgcn_mfma_f32_16x16x32_f16(
                        af[i].h, bf[j].h, acc[i][j], 0, 0, 0);
        }
        __syncthreads();
    }

    // ---- epilogue (R6 form) ----
    {   // zero hist region with b128 (1024 uint4 = 4 per thread)
        const uint4 zz = uint4{0u, 0u, 0u, 0u};
        sh4[t] = zz; sh4[t + 256] = zz; sh4[t + 512] = zz; sh4[t + 768] = zz;
    }
    if (t < 128) rmx[t] = 0u;
    if (t == 0) { ctrl[0] = 0u; ctrl[1] = 0u; }
    __syncthreads();

    // rowmax + hist (C/D layout: col = lane&15, row = quad*4 + reg)
    const unsigned rep = t & 1;
    #pragma unroll
    for (int i = 0; i < 4; ++i) {
        #pragma unroll
        for (int r = 0; r < 4; ++r) {
            int row = ((Ibase + i) << 4) + (quad << 2) + r;
            unsigned km = max(max(fkey(acc[i][0][r]), fkey(acc[i][1][r])),
                              max(fkey(acc[i][2][r]), fkey(acc[i][3][r])));
            #pragma unroll
            for (int off = 1; off < 16; off <<= 1)
                km = max(km, (unsigned)__shfl_xor((int)km, off, 64));
            if (m == 0) atomicMax(&rmx[row], km);
            #pragma unroll
            for (int j = 0; j < 4; ++j)
                atomicAdd(&sw[((fkey(acc[i][j][r]) >> 21) << 1) | rep], 1u);
        }
    }
    __syncthreads();

    // combine replicas -> chunk sums; push nonzero bins to global ghist
    {
        unsigned* gh = ghist + (size_t)z * 2048;
        unsigned s = 0;
        #pragma unroll
        for (int j = 0; j < 8; ++j) {
            int bin = (t << 3) + j;
            unsigned c = sw[bin * 2] + sw[bin * 2 + 1];
            s += c;
            if (c) atomicAdd(&gh[bin], c);
        }
        scanS[t] = s;
    }
    __syncthreads();

    // wave 0: local cutoff bin via shuffle suffix-scan (no barriers)
    if (w == 0) {
        unsigned cs[4]; unsigned tot = 0;
        #pragma unroll
        for (int j = 0; j < 4; ++j) { cs[j] = scanS[(lane << 2) + j]; tot += cs[j]; }
        unsigned suf = tot;
        #pragma unroll
        for (int off = 1; off < 64; off <<= 1) {
            unsigned o = (unsigned)__shfl_down((int)suf, off, 64);
            suf += (lane + off < 64) ? o : 0u;
        }
        unsigned Snx = (unsigned)__shfl_down((int)suf, 1, 64);
        if (lane == 63) Snx = 0u;
        if (suf >= K_TOP && Snx < K_TOP) {
            unsigned cum = Snx;
            unsigned lbv = 0u;
            bool done = false;
            for (int j = 3; j >= 0 && !done; --j) {
                int chunk = (lane << 2) + j;
                unsigned cj = cs[j];
                if (cum + cj < K_TOP) { cum += cj; continue; }
                for (int bb = 7; bb >= 0; --bb) {
                    int bin = (chunk << 3) + bb;
                    unsigned hh = sw[bin * 2] + sw[bin * 2 + 1];
                    if (cum + hh >= K_TOP) { lbv = (unsigned)bin; done = true; break; }
                    cum += hh;
                }
            }
            ctrl[0] = lbv;
        }
    }
    __syncthreads();
    const unsigned lb = ctrl[0];

    // compact keys with bin >= lb (hist region dead; reuse as buffer)
    unsigned* buf = sw;
    #pragma unroll
    for (int i = 0; i < 4; ++i)
        #pragma unroll
        for (int j = 0; j < 4; ++j)
            #pragma unroll
            for (int r = 0; r < 4; ++r) {
                unsigned u = fkey(acc[i][j][r]);
                if ((u >> 21) >= lb) {
                    unsigned idx = atomicAdd(&ctrl[1], 1u);
                    if (idx < CAPB) buf[idx] = u;
                }
            }
    __syncthreads();
    const int slot = z * 16 + bx;
    unsigned c = min(ctrl[1], (unsigned)CAPB);
    for (unsigned i = t; i < c; i += 256) cand[(size_t)slot * CAPB + i] = buf[i];
    if (t == 0) candCnt[slot] = c;
    if (t < 128) rowmaxLocal[(size_t)slot * N_ + t] = rmx[t];
}

// K2: per (batch,side): exact global cutoff from ghist, resolve within the
// cutoff bin via low-21-bit radix over filtered candidates, then score.
__global__ __launch_bounds__(256) void select_score(
    const unsigned* __restrict__ ghist, const unsigned* __restrict__ cand,
    const unsigned* __restrict__ candCnt, const unsigned* __restrict__ rowmaxLocal,
    float* __restrict__ sc, int nb, int b0)
{
    __shared__ unsigned lbuf[SELCAP];
    __shared__ unsigned scanS[256];
    __shared__ unsigned h[256];
    __shared__ unsigned cnts[16];
    __shared__ unsigned ctrl[8];   // 0 gbin, 1 krem, 2 lcnt, 3..5 digits
    __shared__ float s_sum[4], s_cnt[4];
    const int z   = blockIdx.x;
    const int tid = threadIdx.x;
    const int lane = tid & 63;
    const int w    = tid >> 6;
    const unsigned* gh = ghist + (size_t)z * 2048;

    if (tid < 16) cnts[tid] = candCnt[z * 16 + tid];
    if (tid == 0) { ctrl[2] = 0u; ctrl[3] = 0u; ctrl[4] = 0u; ctrl[5] = 0u; }
    {
        unsigned s = 0;
        #pragma unroll
        for (int j = 0; j < 8; ++j) s += gh[(tid << 3) + j];
        scanS[tid] = s;
    }
    __syncthreads();
    if (w == 0) {
        unsigned cs[4]; unsigned tot = 0;
        #pragma unroll
        for (int j = 0; j < 4; ++j) { cs[j] = scanS[(lane << 2) + j]; tot += cs[j]; }
        unsigned suf = tot;
        #pragma unroll
        for (int off = 1; off < 64; off <<= 1) {
            unsigned o = (unsigned)__shfl_down((int)suf, off, 64);
            suf += (lane + off < 64) ? o : 0u;
        }
        unsigned Snx = (unsigned)__shfl_down((int)suf, 1, 64);
        if (lane == 63) Snx = 0u;
        if (suf >= K_TOP && Snx < K_TOP) {
            unsigned cum = Snx;
            for (int j = 3; j >= 0; --j) {
                int chunk = (lane << 2) + j;
                if (cum + cs[j] < K_TOP) { cum += cs[j]; continue; }
                for (int bb = 7; bb >= 0; --bb) {
                    int bin = (chunk << 3) + bb;
                    unsigned hh = gh[bin];
                    if (cum + hh >= K_TOP) {
                        ctrl[0] = (unsigned)bin;
                        ctrl[1] = K_TOP - cum;
                        j = -1; break;
                    }
                    cum += hh;
                }
            }
        }
    }
    __syncthreads();
    const unsigned gbin = ctrl[0];

    // rowmax combine + filter candidates to the cutoff bin
    unsigned myrm = 0u;
    if (tid < N_) {
        #pragma unroll
        for (int s = 0; s < 16; ++s)
            myrm = max(myrm, rowmaxLocal[(size_t)(z * 16 + s) * N_ + tid]);
    }
    for (int s = 0; s < 16; ++s) {
        const unsigned* src = cand + (size_t)(z * 16 + s) * CAPB;
        unsigned cnt = cnts[s];
        for (unsigned i = tid; i < cnt; i += 256) {
            unsigned u = src[i];
            if ((u >> 21) == gbin) {
                unsigned idx = atomicAdd(&ctrl[2], 1u);
                if (idx < SELCAP) lbuf[idx] = u;
            }
        }
    }
    __syncthreads();
    const int total = (int)min(ctrl[2], (unsigned)SELCAP);

    // 3-round radix on low 21 bits: digits [20:13], [12:5], [4:0]
    for (int r = 0; r < 3; ++r) {
        h[tid] = 0u;
        __syncthreads();
        const unsigned d1 = ctrl[3], d2 = ctrl[4];
        const unsigned k = ctrl[1];
        for (int i = tid; i < total; i += 256) {
            unsigned u = lbuf[i];
            unsigned dig; bool ok;
            if (r == 0)      { ok = true;                                 dig = (u >> 13) & 255u; }
            else if (r == 1) { ok = ((u >> 13) & 255u) == d1;             dig = (u >> 5) & 255u; }
            else             { ok = ((u >> 5) & 0xFFFFu) == ((d1 << 8) | d2); dig = u & 31u; }
            if (ok) atomicAdd(&h[dig], 1u);
        }
        __syncthreads();
        if (w == 0) {
            unsigned cs[4]; unsigned tot = 0;
            #pragma unroll
            for (int j = 0; j < 4; ++j) { cs[j] = h[(lane << 2) + j]; tot += cs[j]; }
            unsigned suf = tot;
            #pragma unroll
            for (int off = 1; off < 64; off <<= 1) {
                unsigned o = (unsigned)__shfl_down((int)suf, off, 64);
                suf += (lane + off < 64) ? o : 0u;
            }
            unsigned Snx = (unsigned)__shfl_down((int)suf, 1, 64);
            if (lane == 63) Snx = 0u;
            if (suf >= k && Snx < k) {
                unsigned cum = Snx;
                for (int j = 3; j >= 0; --j) {
                    unsigned dg = (unsigned)((lane << 2) + j);
                    if (cum + cs[j] < k) { cum += cs[j]; continue; }
                    ctrl[3 + r] = dg;
                    ctrl[1] = k - cum;
                    break;
                }
            }
        }
        __syncthreads();
    }
    const unsigned T = (gbin << 21) | (ctrl[3] << 13) | (ctrl[4] << 5) | ctrl[5];

    // score from 128 row maxima
    float v = 0.f, c = 0.f;
    if (tid < N_ && myrm >= T) { v = fmaxf(unkey(myrm), 0.f); c = 1.f; }
    #pragma unroll
    for (int off = 32; off > 0; off >>= 1) {
        v += __shfl_xor(v, off, 64);
        c += __shfl_xor(c, off, 64);
    }
    if ((tid & 63) == 0) { s_sum[w] = v; s_cnt[w] = c; }
    __syncthreads();
    if (tid == 0) {
        float Sv = s_sum[0] + s_sum[1] + s_sum[2] + s_sum[3];
        float Cv = s_cnt[0] + s_cnt[1] + s_cnt[2] + s_cnt[3];
        int b = b0 + ((z < nb) ? z : z - nb);
        int side = (z < nb) ? 0 : 1;
        sc[side * B_ + b] = Sv / fmaxf(Cv, 0.001f);
    }
}

// K3: loss = mean_b softplus(neg - pos)
__global__ __launch_bounds__(64) void final_loss(
    const float* __restrict__ sc, float* __restrict__ out)
{
    int b = threadIdx.x;
    float x = sc[B_ + b] - sc[b];
    float sp = (x > 20.f) ? x : log1pf(expf(x));
    #pragma unroll
    for (int o = 32; o > 0; o >>= 1) sp += __shfl_xor(sp, o, 64);
    if (b == 0) out[0] = sp * (1.f / B_);
}

extern "C" void kernel_launch(void* const* d_in, const int* in_sizes, int n_in,
                              void* d_out, int out_size, void* d_ws, size_t ws_size,
                              hipStream_t stream) {
    const float* q    = (const float*)d_in[0];
    const float* dpos = (const float*)d_in[1];
    const float* dneg = (const float*)d_in[2];
    float* out = (float*)d_out;
    char* ws = (char*)d_ws;

    // per-batch words (x2 sides): ghist 2048 + rowmax 16*128 + cand 16*CAPB + cnt 16
    const size_t per_batch = 2ull * (2048 + 16 * N_ + 16 * CAPB + 16) * 4;
    const size_t fixed = 2 * B_ * sizeof(float) + 256;
    size_t avail = (ws_size > fixed) ? (ws_size - fixed) : 0;
    int Bc = (int)(avail / per_batch);
    if (Bc > B_) Bc = B_;
    if (Bc < 1) Bc = 1;

    char* p = ws;
    float*    sc          = (float*)p;    p += ((2 * B_ * 4 + 255) / 256) * 256;
    unsigned* ghist       = (unsigned*)p; p += (size_t)2 * Bc * 2048 * 4;
    unsigned* rowmaxLocal = (unsigned*)p; p += (size_t)2 * Bc * 16 * N_ * 4;
    unsigned* candCnt     = (unsigned*)p; p += (size_t)2 * Bc * 16 * 4;
    unsigned* cand        = (unsigned*)p; p += (size_t)2 * Bc * 16 * CAPB * 4;

    for (int b0 = 0; b0 < B_; b0 += Bc) {
        int nb = (B_ - b0 < Bc) ? (B_ - b0) : Bc;
        (void)hipMemsetAsync(ghist, 0, (size_t)2 * nb * 2048 * 4, stream);
        gemm_fused<<<dim3(S_ / 128, 1, 2 * nb), 256, 0, stream>>>(
            q, dpos, dneg, nb, b0, rowmaxLocal, cand, candCnt, ghist);
        select_score<<<2 * nb, 256, 0, stream>>>(
            ghist, cand, candCnt, rowmaxLocal, sc, nb, b0);
    }
    final_loss<<<1, 64, 0, stream>>>(sc, out);
}